// Round 18
// baseline (48.825 us; speedup 1.0000x reference)
//
#include <hip/hip_runtime.h>

#define NWIDTH 299592
#define NOUT   51360

typedef unsigned long long ull;
typedef unsigned short u16;

// Lyndon combinatorics (Witt formula; validated by rounds 8-17 passes):
__device__ const int g_B2[8] = {8, 15, 21, 26, 30, 33, 35, 36};
__device__ const int g_B3[8] = {36, 92, 134, 164, 184, 196, 202, 204};
__device__ const int g_B4[8] = {204, 624, 897, 1062, 1152, 1194, 1209, 1212};
__device__ const int g_B5[8] = {1212, 4404, 6210, 7140, 7560, 7716, 7758, 7764};
__device__ const int g_C6[8] = {0, 24052, 35861, 41016, 42926, 43480, 43587, 43596};
// 16 balanced units per batch: j1 counts {6,4,2,1,1,1,1}; first unit of each
// j1 group also emits the algebra (levels 1..5) outputs.
__device__ const int g_uj1[16] = {0,0,0,0,0,0, 1,1,1,1, 2,2, 3, 4, 5, 6};
__device__ const int g_ur0[16] = {0, 4009, 8018, 12027, 16036, 20044,
                                  24052, 27005, 29957, 32909,
                                  35861, 38439, 41016, 42926, 43480, 43587};
__device__ const int g_ur1[16] = {4009, 8018, 12027, 16036, 20044, 24052,
                                  27005, 29957, 32909, 35861,
                                  38439, 41016, 42926, 43480, 43587, 43596};
__device__ const int g_ualg[16] = {1,0,0,0,0,0, 1,0,0,0, 1,0, 1, 1, 1, 1};

__device__ __forceinline__ bool is_lyndon6(unsigned p) {
  const unsigned mask = (1u << 18) - 1u;
#pragma unroll
  for (int k = 1; k < 6; ++k) {
    unsigned rot = ((p << (3 * k)) & mask) | (p >> (18 - 3 * k));
    if (p >= rot) return false;
  }
  return true;
}
__device__ __forceinline__ bool is_lyndon(unsigned p, int n) {
  const unsigned nb = 3u * (unsigned)n;
  const unsigned mask = (1u << nb) - 1u;
  for (int k = 1; k < n; ++k) {
    unsigned rot = ((p << (3 * k)) & mask) | (p >> (nb - 3 * k));
    if (p >= rot) return false;
  }
  return true;
}

// ---- prep: pos16[global_rank] = 15-bit position within the j1 slice ----
__global__ __launch_bounds__(1024) void lyndon_prep(u16* __restrict__ pos16) {
  __shared__ int wsum[16];
  const int tid = threadIdx.x, lane = tid & 63, wv = tid >> 6;
  const int j = blockIdx.x;
  const unsigned pb = ((unsigned)j << 15) | ((unsigned)tid << 5);
  unsigned lm = 0;
  int c = 0;
  for (int i = 0; i < 32; ++i)
    if (is_lyndon6(pb | (unsigned)i)) { lm |= 1u << i; ++c; }
  int pref = c;
  for (int d = 1; d < 64; d <<= 1) { int t = __shfl_up(pref, d); if (lane >= d) pref += t; }
  if (lane == 63) wsum[wv] = pref;
  __syncthreads();
  int base = 0;
  for (int i = 0; i < wv; ++i) base += wsum[i];
  int ex = g_C6[j] + base + pref - c;
  unsigned m = lm;
  const int p0 = tid << 5;
  while (m) {
    const int bit = __builtin_ctz(m);
    pos16[ex++] = (u16)(p0 + bit);
    m &= m - 1;
  }
}

// ---- main LDS layout (floats): 7872 = 31.5 KiB ----
#define L_S3  0       // 512
#define L_S2  512     // 64
#define L_S1  576     // 8
#define L_A2  584     // 8
#define L_A3  592     // 64
#define L_A4  656     // 512
#define L_W2  1168    // 8
#define L_W3  1176    // 64
#define L_W4  1240    // 512
#define L_W4i 1752    // 8 int
#define L_W5i 1760    // 8 int
#define L_A5  1768    // 4096 (16B aligned)
#define L_PL  5864    // u16[4016] = 2008 floats (16B aligned: 5864*4%16==0)
#define L_TOT 7872

// grid 1024 = 8 XCD x 8 batch x 16 units. Closed-form algebra (3 barriers),
// then rank-driven L6 eval: 8 consecutive ranks per thread, one pass, two
// 4-eval batches each issuing 12 independent scattered loads (MLP ~12).
__global__ __launch_bounds__(512)
void logsig_fused(const float* __restrict__ sig,
                  const u16* __restrict__ pos16,
                  float* __restrict__ out) {
  __shared__ __align__(16) float sm[L_TOT];
  int* W4i = (int*)(sm + L_W4i);
  int* W5i = (int*)(sm + L_W5i);
  u16* PL  = (u16*)(sm + L_PL);

  const int tid = threadIdx.x, lane = tid & 63, wv = tid >> 6;
  const int bid = blockIdx.x;
  const int xcd = bid & 7;
  const int rr  = bid >> 3;            // 0..127
  const int b   = xcd * 8 + (rr >> 4);
  const int u   = rr & 15;
  const int j1  = g_uj1[u];
  const bool isalg = g_ualg[u] != 0;
  const int r0 = g_ur0[u], r1 = g_ur1[u];
  const int cnt = r1 - r0;

  const float* __restrict__ S   = sig + (size_t)b * NWIDTH;
  const float* __restrict__ S4g = S + 584;
  const float* __restrict__ S5g = S + 4680;
  const float* __restrict__ S6j = S + 37448 + (size_t)j1 * 32768;
  float* __restrict__ outb = out + (size_t)b * NOUT;

  const float p1 = S[j1];
  const float c2 = -0.5f, c3 = 1.f / 3.f, c4 = -0.25f, c5 = 0.2f, c6 = -1.f / 6.f;
  const float c2p1 = c2 * p1;
  const float c3p1 = c3 * p1;
  const int q4 = tid << 2;

  // ---- stage ----
  sm[L_S3 + tid] = S[72 + tid];
  if (tid < 64) sm[L_S2 + tid] = S[8 + tid];
  if (tid < 8)  sm[L_S1 + tid] = S[tid];
  // PL zero-padded to 4016 so the eval pass needs no per-element load guards
  for (int i = tid; i < 4016; i += 512) PL[i] = (i < cnt) ? pos16[r0 + i] : (u16)0;
  const float s4p = S4g[j1 * 512 + tid];        // S4[j1 | x=tid] (coalesced)
  float p5[8];                                  // S5[j1 | q], 2x4 halves
  {
    float4 va = *(const float4*)(S5g + j1 * 4096 + q4);
    float4 vb = *(const float4*)(S5g + j1 * 4096 + 2048 + q4);
    p5[0] = va.x; p5[1] = va.y; p5[2] = va.z; p5[3] = va.w;
    p5[4] = vb.x; p5[5] = vb.y; p5[6] = vb.z; p5[7] = vb.w;
  }
  float4 s4qa, s4qb;                            // S4[q] for the 2 halves
  s4qa = *(const float4*)(S4g + q4);
  s4qb = *(const float4*)(S4g + 2048 + q4);

  // ---- gather flags for levels 4,5 (overlaps staging) ----
  ull m4 = 0;
  unsigned fm5a = 0, fm5b = 0;
  int exA = 0, exB = 0;
  if (isalg) {
    bool f4 = is_lyndon(((unsigned)j1 << 9) | (unsigned)tid, 4);
    m4 = __ballot(f4);
    if (lane == 0) W4i[wv] = __popcll(m4);
    int c5a = 0, c5b = 0;
#pragma unroll
    for (int e = 0; e < 4; ++e) {
      if (is_lyndon(((unsigned)j1 << 12) | (unsigned)(q4 + e), 5)) { fm5a |= 1u << e; ++c5a; }
      if (is_lyndon(((unsigned)j1 << 12) | (unsigned)(2048 + q4 + e), 5)) { fm5b |= 1u << e; ++c5b; }
    }
    int prefpk = c5a | (c5b << 16);
    for (int d = 1; d < 64; d <<= 1) { int t = __shfl_up(prefpk, d); if (lane >= d) prefpk += t; }
    if (lane == 63) W5i[wv] = prefpk;
    exA = (prefpk & 0xffff) - c5a;
    exB = (prefpk >> 16) - c5b;
  }
  __syncthreads();   // barrier 1: S-caches + PL visible

  // ---- closed-form A2..A4 / W2..W4 ----
  {
    const int x = tid;                               // 3-letter suffix j2j3j4
    const float s1_4 = sm[L_S1 + (x & 7)];
    const float s1_3 = sm[L_S1 + ((x >> 3) & 7)];
    const float s1_2 = sm[L_S1 + (x >> 6)];
    const float s3p  = sm[L_S3 + j1 * 64 + (x >> 3)];   // S3[j1 j2 j3]
    const float s2p  = sm[L_S2 + j1 * 8 + (x >> 6)];    // S2[j1 j2]
    const float w4_2 = s3p * s1_4 + s2p * sm[L_S2 + (x & 63)] + p1 * sm[L_S3 + x];
    const float w4_3 = (s2p * s1_3 + p1 * sm[L_S2 + (x >> 3)]) * s1_4
                     + p1 * s1_2 * sm[L_S2 + (x & 63)];
    const float w4_4 = p1 * s1_2 * s1_3 * s1_4;
    sm[L_A4 + x] = c2 * s4p + c3 * w4_2 + c4 * w4_3 + c5 * w4_4;
    sm[L_W4 + x] = c3 * s4p + c4 * w4_2 + c5 * w4_3 + c6 * w4_4;
  }
  if (tid < 64) {
    const int y = tid;                               // j2j3
    const float w3_2 = sm[L_S2 + j1 * 8 + (y >> 3)] * sm[L_S1 + (y & 7)]
                     + p1 * sm[L_S2 + y];
    const float w3_3 = p1 * sm[L_S1 + (y >> 3)] * sm[L_S1 + (y & 7)];
    const float s3py = sm[L_S3 + j1 * 64 + y];
    sm[L_A3 + y] = c2 * s3py + c3 * w3_2 + c4 * w3_3;
    sm[L_W3 + y] = c3 * s3py + c4 * w3_2 + c5 * w3_3;
  }
  if (tid < 8) {
    const int z = tid;
    const float s2pz = sm[L_S2 + j1 * 8 + z];
    const float s1z  = sm[L_S1 + z];
    sm[L_A2 + z] = c2 * s2pz + c3 * p1 * s1z;
    sm[L_W2 + z] = c3 * s2pz + c4 * p1 * s1z;
  }
  __syncthreads();   // barrier 2: A2..A4 / W2..W4 visible

  const float s1t = sm[L_S1 + (tid & 7)];
  float s1q4[4];
#pragma unroll
  for (int e = 0; e < 4; ++e) s1q4[e] = sm[L_S1 + ((tid & 1) << 2) + e];

  // ---- A5 (to LDS) + L5 (regs), 2x4 halves ----
  float l5a[4], l5b[4];
  {
    const float W4a = sm[L_W4 + (tid >> 1)],       W4b = sm[L_W4 + 256 + (tid >> 1)];
    const float A4a = sm[L_A4 + (tid >> 1)],       A4b = sm[L_A4 + 256 + (tid >> 1)];
    const float W3a = sm[L_W3 + (tid >> 4)],       W3b = sm[L_W3 + 32 + (tid >> 4)];
    const float A3a = sm[L_A3 + (tid >> 4)],       A3b = sm[L_A3 + 32 + (tid >> 4)];
    const float W2a = sm[L_W2 + (tid >> 7)],       W2b = sm[L_W2 + 4 + (tid >> 7)];
    const float A2a = sm[L_A2 + (tid >> 7)],       A2b = sm[L_A2 + 4 + (tid >> 7)];
    const float4 s2v = *(const float4*)(sm + L_S2 + (q4 & 63));
    const float4 s3v = *(const float4*)(sm + L_S3 + (q4 & 511));
    const float s2q[4] = {s2v.x, s2v.y, s2v.z, s2v.w};
    const float s3q[4] = {s3v.x, s3v.y, s3v.z, s3v.w};
    const float s4a[4] = {s4qa.x, s4qa.y, s4qa.z, s4qa.w};
    const float s4b[4] = {s4qb.x, s4qb.y, s4qb.z, s4qb.w};
    float a5A[4], a5B[4];
#pragma unroll
    for (int e = 0; e < 4; ++e) {
      a5A[e] = c2 * p5[e]     + W4a * s1q4[e] + W3a * s2q[e] + W2a * s3q[e] + c3p1 * s4a[e];
      a5B[e] = c2 * p5[4 + e] + W4b * s1q4[e] + W3b * s2q[e] + W2b * s3q[e] + c3p1 * s4b[e];
      l5a[e] = p5[e]     + A4a * s1q4[e] + A3a * s2q[e] + A2a * s3q[e] + c2p1 * s4a[e];
      l5b[e] = p5[4 + e] + A4b * s1q4[e] + A3b * s2q[e] + A2b * s3q[e] + c2p1 * s4b[e];
    }
    *(float4*)(sm + L_A5 + q4)        = make_float4(a5A[0], a5A[1], a5A[2], a5A[3]);
    *(float4*)(sm + L_A5 + 2048 + q4) = make_float4(a5B[0], a5B[1], a5B[2], a5B[3]);
  }

  if (isalg) {
    // ---- closed-form L2..L4 + emit levels 1..5 ----
    float l2v = 0.f, l3v = 0.f;
    if (tid < 8)
      l2v = sm[L_S2 + j1 * 8 + tid] + c2p1 * s1t;
    if (tid < 64)
      l3v = sm[L_S3 + j1 * 64 + tid] + sm[L_A2 + (tid >> 3)] * s1t
          + c2p1 * sm[L_S2 + tid];
    const float l4v = s4p + sm[L_A3 + (tid >> 3)] * s1t
                    + sm[L_A2 + (tid >> 6)] * sm[L_S2 + (tid & 63)]
                    + c2p1 * sm[L_S3 + tid];
    if (tid == 0) {
      outb[j1] = p1;
      if (j1 == 0) outb[7] = sm[L_S1 + 7];
    }
    if (tid < 8 && tid > j1) outb[g_B2[j1] + tid - j1 - 1] = l2v;
    if (tid < 64) {
      bool f3 = is_lyndon(((unsigned)j1 << 6) | (unsigned)tid, 3);
      ull m3 = __ballot(f3);
      if (f3) outb[g_B3[j1] + __popcll(m3 & ((1ull << lane) - 1ull))] = l3v;
    }
    {
      int base = 0;
      for (int i = 0; i < wv; ++i) base += W4i[i];
      if ((m4 >> lane) & 1ull)
        outb[g_B4[j1] + base + __popcll(m4 & ((1ull << lane) - 1ull))] = l4v;
    }
    {
      int baseA = 0, baseB = 0, totalA = 0;
#pragma unroll
      for (int i = 0; i < 8; ++i) {
        int w = W5i[i];
        totalA += w & 0xffff;
        if (i < wv) { baseA += w & 0xffff; baseB += w >> 16; }
      }
      int slotA = g_B5[j1] + baseA + exA;
      int slotB = g_B5[j1] + totalA + baseB + exB;
#pragma unroll
      for (int e = 0; e < 4; ++e)
        if ((fm5a >> e) & 1u) outb[slotA++] = l5a[e];
#pragma unroll
      for (int e = 0; e < 4; ++e)
        if ((fm5b >> e) & 1u) outb[slotB++] = l5b[e];
    }
  }
  __syncthreads();   // barrier 3: A5 visible

  // ---- level 6: 8 consecutive ranks/thread, one pass, batched loads ----
  float* __restrict__ outr = outb + 7764 + r0;
  const int ib = tid << 3;
  if (ib < cnt) {
    const uint4 pk = *(const uint4*)(PL + ib);   // 8 packed u16 positions
    int pl[8];
    pl[0] = (int)(pk.x & 0xffffu);  pl[1] = (int)(pk.x >> 16);
    pl[2] = (int)(pk.y & 0xffffu);  pl[3] = (int)(pk.y >> 16);
    pl[4] = (int)(pk.z & 0xffffu);  pl[5] = (int)(pk.z >> 16);
    pl[6] = (int)(pk.w & 0xffffu);  pl[7] = (int)(pk.w >> 16);
#pragma unroll
    for (int h = 0; h < 2; ++h) {
      float x6[4], x5[4], x4[4];
#pragma unroll
      for (int e = 0; e < 4; ++e) {              // issue 12 independent loads
        const int p = pl[h * 4 + e];
        x6[e] = S6j[p];
        x5[e] = S5g[p];
        x4[e] = S4g[p & 4095];
      }
#pragma unroll
      for (int e = 0; e < 4; ++e) {
        const int k = h * 4 + e;
        const int p = pl[k];
        float v = x6[e]
                + sm[L_A5 + (p >> 3)] * sm[L_S1 + (p & 7)]
                + sm[L_A4 + (p >> 6)] * sm[L_S2 + (p & 63)]
                + sm[L_A3 + (p >> 9)] * sm[L_S3 + (p & 511)]
                + sm[L_A2 + (p >> 12)] * x4[e]
                + c2p1 * x5[e];
        if (ib + k < cnt) outr[ib + k] = v;
      }
    }
  }
}

// ---------- launch ----------
// d_ws: pos16[43596] u16 (~85 KB)

extern "C" void kernel_launch(void* const* d_in, const int* in_sizes, int n_in,
                              void* d_out, int out_size, void* d_ws, size_t ws_size,
                              hipStream_t stream) {
  const float* sig = (const float*)d_in[0];
  float* out = (float*)d_out;
  u16* pos16 = (u16*)d_ws;

  lyndon_prep<<<7, 1024, 0, stream>>>(pos16);
  logsig_fused<<<1024, 512, 0, stream>>>(sig, pos16, out);
}

// Round 19
// 40.174 us; speedup vs baseline: 1.2153x; 1.2153x over previous
//
#include <hip/hip_runtime.h>

#define NWIDTH 299592
#define NOUT   51360

typedef unsigned long long ull;
typedef unsigned short u16;

// Lyndon combinatorics (Witt formula; validated by rounds 8-18 passes):
__device__ const int g_B2[8] = {8, 15, 21, 26, 30, 33, 35, 36};
__device__ const int g_B3[8] = {36, 92, 134, 164, 184, 196, 202, 204};
__device__ const int g_B4[8] = {204, 624, 897, 1062, 1152, 1194, 1209, 1212};
__device__ const int g_B5[8] = {1212, 4404, 6210, 7140, 7560, 7716, 7758, 7764};
__device__ const int g_C6[8] = {0, 24052, 35861, 41016, 42926, 43480, 43587, 43596};
// 16 balanced units per batch: j1 counts {6,4,2,1,1,1,1}; first unit of each
// j1 group also emits the algebra (levels 1..5) outputs.
__device__ const int g_uj1[16] = {0,0,0,0,0,0, 1,1,1,1, 2,2, 3, 4, 5, 6};
__device__ const int g_ur0[16] = {0, 4009, 8018, 12027, 16036, 20044,
                                  24052, 27005, 29957, 32909,
                                  35861, 38439, 41016, 42926, 43480, 43587};
__device__ const int g_ur1[16] = {4009, 8018, 12027, 16036, 20044, 24052,
                                  27005, 29957, 32909, 35861,
                                  38439, 41016, 42926, 43480, 43587, 43596};
__device__ const int g_ualg[16] = {1,0,0,0,0,0, 1,0,0,0, 1,0, 1, 1, 1, 1};

__device__ __forceinline__ bool is_lyndon6(unsigned p) {
  const unsigned mask = (1u << 18) - 1u;
#pragma unroll
  for (int k = 1; k < 6; ++k) {
    unsigned rot = ((p << (3 * k)) & mask) | (p >> (18 - 3 * k));
    if (p >= rot) return false;
  }
  return true;
}
__device__ __forceinline__ bool is_lyndon(unsigned p, int n) {
  const unsigned nb = 3u * (unsigned)n;
  const unsigned mask = (1u << nb) - 1u;
  for (int k = 1; k < n; ++k) {
    unsigned rot = ((p << (3 * k)) & mask) | (p >> (nb - 3 * k));
    if (p >= rot) return false;
  }
  return true;
}

// ---- prep: pos16[global_rank] = 15-bit position within the j1 slice ----
__global__ __launch_bounds__(1024) void lyndon_prep(u16* __restrict__ pos16) {
  __shared__ int wsum[16];
  const int tid = threadIdx.x, lane = tid & 63, wv = tid >> 6;
  const int j = blockIdx.x;
  const unsigned pb = ((unsigned)j << 15) | ((unsigned)tid << 5);
  unsigned lm = 0;
  int c = 0;
  for (int i = 0; i < 32; ++i)
    if (is_lyndon6(pb | (unsigned)i)) { lm |= 1u << i; ++c; }
  int pref = c;
  for (int d = 1; d < 64; d <<= 1) { int t = __shfl_up(pref, d); if (lane >= d) pref += t; }
  if (lane == 63) wsum[wv] = pref;
  __syncthreads();
  int base = 0;
  for (int i = 0; i < wv; ++i) base += wsum[i];
  int ex = g_C6[j] + base + pref - c;
  unsigned m = lm;
  const int p0 = tid << 5;
  while (m) {
    const int bit = __builtin_ctz(m);
    pos16[ex++] = (u16)(p0 + bit);
    m &= m - 1;
  }
}

// ---- main LDS layout (floats): 7872 = 31.5 KiB ----
#define L_S3  0       // 512
#define L_S2  512     // 64
#define L_S1  576     // 8
#define L_A2  584     // 8
#define L_A3  592     // 64
#define L_A4  656     // 512
#define L_W2  1168    // 8
#define L_W3  1176    // 64
#define L_W4  1240    // 512
#define L_W4i 1752    // 8 int
#define L_W5i 1760    // 8 int
#define L_A5  1768    // 4096 (16B aligned)
#define L_PL  5864    // u16[4016] = 2008 floats
#define L_TOT 7872

// grid 1024 = 8 XCD x 8 batch x 16 units. Closed-form algebra (no Horner
// recursion): A2..A4 and coefficient-shifted W2..W4 are direct polynomials in
// the staged S-values; A5[q] = c2*S5[j1 q] + W4[q>>3]*S1 + W3[q>>6]*S2 +
// W2[q>>9]*S3 + c3*p1*S4[q]. 3 barriers total. Eval loop deliberately ROLLED:
// R14/R18 showed unrolling trades occupancy for MLP at a net loss here.
__global__ __launch_bounds__(512)
void logsig_fused(const float* __restrict__ sig,
                  const u16* __restrict__ pos16,
                  float* __restrict__ out) {
  __shared__ __align__(16) float sm[L_TOT];
  int* W4i = (int*)(sm + L_W4i);
  int* W5i = (int*)(sm + L_W5i);
  u16* PL  = (u16*)(sm + L_PL);

  const int tid = threadIdx.x, lane = tid & 63, wv = tid >> 6;
  const int bid = blockIdx.x;
  const int xcd = bid & 7;
  const int rr  = bid >> 3;            // 0..127
  const int b   = xcd * 8 + (rr >> 4);
  const int u   = rr & 15;
  const int j1  = g_uj1[u];
  const bool isalg = g_ualg[u] != 0;
  const int r0 = g_ur0[u], r1 = g_ur1[u];
  const int cnt = r1 - r0;

  const float* __restrict__ S   = sig + (size_t)b * NWIDTH;
  const float* __restrict__ S4g = S + 584;
  const float* __restrict__ S5g = S + 4680;
  const float* __restrict__ S6j = S + 37448 + (size_t)j1 * 32768;
  float* __restrict__ outb = out + (size_t)b * NOUT;

  const float p1 = S[j1];
  const float c2 = -0.5f, c3 = 1.f / 3.f, c4 = -0.25f, c5 = 0.2f, c6 = -1.f / 6.f;
  const float c2p1 = c2 * p1;
  const float c3p1 = c3 * p1;
  const int q4 = tid << 2;

  // ---- stage ----
  sm[L_S3 + tid] = S[72 + tid];
  if (tid < 64) sm[L_S2 + tid] = S[8 + tid];
  if (tid < 8)  sm[L_S1 + tid] = S[tid];
  for (int i = tid; i < cnt; i += 512) PL[i] = pos16[r0 + i];   // prefetch ranks
  const float s4p = S4g[j1 * 512 + tid];        // S4[j1 | x=tid] (coalesced)
  float p5[8];                                  // S5[j1 | q], 2x4 halves
  {
    float4 va = *(const float4*)(S5g + j1 * 4096 + q4);
    float4 vb = *(const float4*)(S5g + j1 * 4096 + 2048 + q4);
    p5[0] = va.x; p5[1] = va.y; p5[2] = va.z; p5[3] = va.w;
    p5[4] = vb.x; p5[5] = vb.y; p5[6] = vb.z; p5[7] = vb.w;
  }
  float4 s4qa, s4qb;                            // S4[q] for the 2 halves
  s4qa = *(const float4*)(S4g + q4);
  s4qb = *(const float4*)(S4g + 2048 + q4);

  // ---- gather flags for levels 4,5 (overlaps staging) ----
  ull m4 = 0;
  unsigned fm5a = 0, fm5b = 0;
  int exA = 0, exB = 0;
  if (isalg) {
    bool f4 = is_lyndon(((unsigned)j1 << 9) | (unsigned)tid, 4);
    m4 = __ballot(f4);
    if (lane == 0) W4i[wv] = __popcll(m4);
    int c5a = 0, c5b = 0;
#pragma unroll
    for (int e = 0; e < 4; ++e) {
      if (is_lyndon(((unsigned)j1 << 12) | (unsigned)(q4 + e), 5)) { fm5a |= 1u << e; ++c5a; }
      if (is_lyndon(((unsigned)j1 << 12) | (unsigned)(2048 + q4 + e), 5)) { fm5b |= 1u << e; ++c5b; }
    }
    int prefpk = c5a | (c5b << 16);
    for (int d = 1; d < 64; d <<= 1) { int t = __shfl_up(prefpk, d); if (lane >= d) prefpk += t; }
    if (lane == 63) W5i[wv] = prefpk;
    exA = (prefpk & 0xffff) - c5a;
    exB = (prefpk >> 16) - c5b;
  }
  __syncthreads();   // barrier 1: S-caches + PL visible

  // ---- closed-form A2..A4 / W2..W4 ----
  {
    const int x = tid;                               // 3-letter suffix j2j3j4
    const float s1_4 = sm[L_S1 + (x & 7)];
    const float s1_3 = sm[L_S1 + ((x >> 3) & 7)];
    const float s1_2 = sm[L_S1 + (x >> 6)];
    const float s3p  = sm[L_S3 + j1 * 64 + (x >> 3)];   // S3[j1 j2 j3]
    const float s2p  = sm[L_S2 + j1 * 8 + (x >> 6)];    // S2[j1 j2]
    const float w4_2 = s3p * s1_4 + s2p * sm[L_S2 + (x & 63)] + p1 * sm[L_S3 + x];
    const float w4_3 = (s2p * s1_3 + p1 * sm[L_S2 + (x >> 3)]) * s1_4
                     + p1 * s1_2 * sm[L_S2 + (x & 63)];
    const float w4_4 = p1 * s1_2 * s1_3 * s1_4;
    sm[L_A4 + x] = c2 * s4p + c3 * w4_2 + c4 * w4_3 + c5 * w4_4;
    sm[L_W4 + x] = c3 * s4p + c4 * w4_2 + c5 * w4_3 + c6 * w4_4;
  }
  if (tid < 64) {
    const int y = tid;                               // j2j3
    const float w3_2 = sm[L_S2 + j1 * 8 + (y >> 3)] * sm[L_S1 + (y & 7)]
                     + p1 * sm[L_S2 + y];
    const float w3_3 = p1 * sm[L_S1 + (y >> 3)] * sm[L_S1 + (y & 7)];
    const float s3py = sm[L_S3 + j1 * 64 + y];
    sm[L_A3 + y] = c2 * s3py + c3 * w3_2 + c4 * w3_3;
    sm[L_W3 + y] = c3 * s3py + c4 * w3_2 + c5 * w3_3;
  }
  if (tid < 8) {
    const int z = tid;
    const float s2pz = sm[L_S2 + j1 * 8 + z];
    const float s1z  = sm[L_S1 + z];
    sm[L_A2 + z] = c2 * s2pz + c3 * p1 * s1z;
    sm[L_W2 + z] = c3 * s2pz + c4 * p1 * s1z;
  }
  __syncthreads();   // barrier 2: A2..A4 / W2..W4 visible

  const float s1t = sm[L_S1 + (tid & 7)];
  float s1q4[4];
#pragma unroll
  for (int e = 0; e < 4; ++e) s1q4[e] = sm[L_S1 + ((tid & 1) << 2) + e];

  // ---- A5 (to LDS) + L5 (regs), 2x4 halves ----
  float l5a[4], l5b[4];
  {
    const float W4a = sm[L_W4 + (tid >> 1)],       W4b = sm[L_W4 + 256 + (tid >> 1)];
    const float A4a = sm[L_A4 + (tid >> 1)],       A4b = sm[L_A4 + 256 + (tid >> 1)];
    const float W3a = sm[L_W3 + (tid >> 4)],       W3b = sm[L_W3 + 32 + (tid >> 4)];
    const float A3a = sm[L_A3 + (tid >> 4)],       A3b = sm[L_A3 + 32 + (tid >> 4)];
    const float W2a = sm[L_W2 + (tid >> 7)],       W2b = sm[L_W2 + 4 + (tid >> 7)];
    const float A2a = sm[L_A2 + (tid >> 7)],       A2b = sm[L_A2 + 4 + (tid >> 7)];
    const float4 s2v = *(const float4*)(sm + L_S2 + (q4 & 63));
    const float4 s3v = *(const float4*)(sm + L_S3 + (q4 & 511));
    const float s2q[4] = {s2v.x, s2v.y, s2v.z, s2v.w};
    const float s3q[4] = {s3v.x, s3v.y, s3v.z, s3v.w};
    const float s4a[4] = {s4qa.x, s4qa.y, s4qa.z, s4qa.w};
    const float s4b[4] = {s4qb.x, s4qb.y, s4qb.z, s4qb.w};
    float a5A[4], a5B[4];
#pragma unroll
    for (int e = 0; e < 4; ++e) {
      a5A[e] = c2 * p5[e]     + W4a * s1q4[e] + W3a * s2q[e] + W2a * s3q[e] + c3p1 * s4a[e];
      a5B[e] = c2 * p5[4 + e] + W4b * s1q4[e] + W3b * s2q[e] + W2b * s3q[e] + c3p1 * s4b[e];
      l5a[e] = p5[e]     + A4a * s1q4[e] + A3a * s2q[e] + A2a * s3q[e] + c2p1 * s4a[e];
      l5b[e] = p5[4 + e] + A4b * s1q4[e] + A3b * s2q[e] + A2b * s3q[e] + c2p1 * s4b[e];
    }
    *(float4*)(sm + L_A5 + q4)        = make_float4(a5A[0], a5A[1], a5A[2], a5A[3]);
    *(float4*)(sm + L_A5 + 2048 + q4) = make_float4(a5B[0], a5B[1], a5B[2], a5B[3]);
  }

  if (isalg) {
    // ---- closed-form L2..L4 + emit levels 1..5 ----
    float l2v = 0.f, l3v = 0.f;
    if (tid < 8)
      l2v = sm[L_S2 + j1 * 8 + tid] + c2p1 * s1t;
    if (tid < 64)
      l3v = sm[L_S3 + j1 * 64 + tid] + sm[L_A2 + (tid >> 3)] * s1t
          + c2p1 * sm[L_S2 + tid];
    const float l4v = s4p + sm[L_A3 + (tid >> 3)] * s1t
                    + sm[L_A2 + (tid >> 6)] * sm[L_S2 + (tid & 63)]
                    + c2p1 * sm[L_S3 + tid];
    if (tid == 0) {
      outb[j1] = p1;
      if (j1 == 0) outb[7] = sm[L_S1 + 7];
    }
    if (tid < 8 && tid > j1) outb[g_B2[j1] + tid - j1 - 1] = l2v;
    if (tid < 64) {
      bool f3 = is_lyndon(((unsigned)j1 << 6) | (unsigned)tid, 3);
      ull m3 = __ballot(f3);
      if (f3) outb[g_B3[j1] + __popcll(m3 & ((1ull << lane) - 1ull))] = l3v;
    }
    {
      int base = 0;
      for (int i = 0; i < wv; ++i) base += W4i[i];
      if ((m4 >> lane) & 1ull)
        outb[g_B4[j1] + base + __popcll(m4 & ((1ull << lane) - 1ull))] = l4v;
    }
    {
      int baseA = 0, baseB = 0, totalA = 0;
#pragma unroll
      for (int i = 0; i < 8; ++i) {
        int w = W5i[i];
        totalA += w & 0xffff;
        if (i < wv) { baseA += w & 0xffff; baseB += w >> 16; }
      }
      int slotA = g_B5[j1] + baseA + exA;
      int slotB = g_B5[j1] + totalA + baseB + exB;
#pragma unroll
      for (int e = 0; e < 4; ++e)
        if ((fm5a >> e) & 1u) outb[slotA++] = l5a[e];
#pragma unroll
      for (int e = 0; e < 4; ++e)
        if ((fm5b >> e) & 1u) outb[slotB++] = l5b[e];
    }
  }
  __syncthreads();   // barrier 3: A5 visible

  // ---- level 6: rank-driven eval, rolled loop, coalesced stores ----
  float* __restrict__ outr = outb + 7764 + r0;
  for (int i = tid; i < cnt; i += 512) {
    const int pl = PL[i];
    float v = S6j[pl]
            + sm[L_A5 + (pl >> 3)] * sm[L_S1 + (pl & 7)]
            + sm[L_A4 + (pl >> 6)] * sm[L_S2 + (pl & 63)]
            + sm[L_A3 + (pl >> 9)] * sm[L_S3 + (pl & 511)]
            + sm[L_A2 + (pl >> 12)] * S4g[pl & 4095]
            + c2p1 * S5g[pl];
    outr[i] = v;
  }
}

// ---------- launch ----------
// d_ws: pos16[43596] u16 (~85 KB)

extern "C" void kernel_launch(void* const* d_in, const int* in_sizes, int n_in,
                              void* d_out, int out_size, void* d_ws, size_t ws_size,
                              hipStream_t stream) {
  const float* sig = (const float*)d_in[0];
  float* out = (float*)d_out;
  u16* pos16 = (u16*)d_ws;

  lyndon_prep<<<7, 1024, 0, stream>>>(pos16);
  logsig_fused<<<1024, 512, 0, stream>>>(sig, pos16, out);
}